// Round 1
// baseline (155.082 us; speedup 1.0000x reference)
//
#include <hip/hip_runtime.h>
#include <hip/hip_bf16.h>

typedef unsigned short u16;
typedef float f32x4 __attribute__((ext_vector_type(4)));
typedef __bf16 bf16x8 __attribute__((ext_vector_type(8)));

union Frag { int4 i; bf16x8 b; };

__device__ inline u16 f2bf(float f) {
  union { float f; unsigned u; } v; v.f = f;
  unsigned r = v.u + 0x7FFFu + ((v.u >> 16) & 1u);
  return (u16)(r >> 16);
}
__device__ inline float bf2f(unsigned b) {
  union { unsigned u; float f; } v; v.u = b << 16;
  return v.f;
}

// ---------------------------------------------------------------------------
// Projection GEMM: Y = X @ W.T + bias   (X: rows x 128 fp32, W: 128x128 fp32)
// mode 0: out bf16 head-major  [b][h][row][16]   (innerShift = log2 rows/batch)
// mode 1: out bf16 transposed  [b][h][16][1024]  (for V)
// mode 2: out fp32 row-major   [row][128]        (final out-proj)
// 64 rows per block, 256 threads (4 waves x 16 rows).
// ---------------------------------------------------------------------------
__global__ __launch_bounds__(256, 2)
void proj_kernel(const float* __restrict__ X, const float* __restrict__ W,
                 const float* __restrict__ bias, void* __restrict__ out,
                 int mode, int innerShift)
{
  __shared__ __attribute__((aligned(16))) u16 smem[26112]; // XL[64][136] @0, WL[128][136] @8704
  u16* XL = smem;
  u16* WL = smem + 64 * 136;

  const int tid = threadIdx.x;
  const int w = tid >> 6, l = tid & 63, lg = l >> 4, lr = l & 15;
  const int rows0 = blockIdx.x * 64;

  // stage X tile (64x128) fp32 -> bf16
  #pragma unroll
  for (int i = 0; i < 8; ++i) {
    int u = tid + i * 256;            // float4 slot in [0,2048)
    int rr = u >> 5, c4 = (u & 31) * 4;
    const float4 xv = *(const float4*)(X + (rows0 + rr) * 128 + c4);
    uint2 p;
    p.x = (unsigned)f2bf(xv.x) | ((unsigned)f2bf(xv.y) << 16);
    p.y = (unsigned)f2bf(xv.z) | ((unsigned)f2bf(xv.w) << 16);
    *(uint2*)(XL + rr * 136 + c4) = p;
  }
  // stage W (128x128) fp32 -> bf16
  #pragma unroll
  for (int i = 0; i < 16; ++i) {
    int u = tid + i * 256;
    int rr = u >> 5, c4 = (u & 31) * 4;
    const float4 xv = *(const float4*)(W + rr * 128 + c4);
    uint2 p;
    p.x = (unsigned)f2bf(xv.x) | ((unsigned)f2bf(xv.y) << 16);
    p.y = (unsigned)f2bf(xv.z) | ((unsigned)f2bf(xv.w) << 16);
    *(uint2*)(WL + rr * 136 + c4) = p;
  }
  __syncthreads();

  Frag a[4];
  #pragma unroll
  for (int kc = 0; kc < 4; ++kc)
    a[kc].i = *(const int4*)(XL + (16 * w + lr) * 136 + kc * 32 + 8 * lg);

  f32x4 acc[8];
  #pragma unroll
  for (int ct = 0; ct < 8; ++ct) {
    f32x4 c = {0.f, 0.f, 0.f, 0.f};
    #pragma unroll
    for (int kc = 0; kc < 4; ++kc) {
      Frag bw;
      bw.i = *(const int4*)(WL + (ct * 16 + lr) * 136 + kc * 32 + 8 * lg);
      c = __builtin_amdgcn_mfma_f32_16x16x32_bf16(a[kc].b, bw.b, c, 0, 0, 0);
    }
    acc[ct] = c;
  }

  if (mode == 2) {
    float* o = (float*)out;
    #pragma unroll
    for (int ct = 0; ct < 8; ++ct) {
      float bn = bias[ct * 16 + lr];
      #pragma unroll
      for (int j = 0; j < 4; ++j) {
        int row = rows0 + 16 * w + 4 * lg + j;
        o[row * 128 + ct * 16 + lr] = acc[ct][j] + bn;
      }
    }
  } else if (mode == 0) {
    u16* o = (u16*)out;
    const int innerMask = (1 << innerShift) - 1;
    #pragma unroll
    for (int ct = 0; ct < 8; ++ct) {
      float bn = bias[ct * 16 + lr];
      #pragma unroll
      for (int j = 0; j < 4; ++j) {
        int row = rows0 + 16 * w + 4 * lg + j;
        int bI = row >> innerShift, r = row & innerMask;
        o[(((bI * 8 + ct) << innerShift) + r) * 16 + lr] = f2bf(acc[ct][j] + bn);
      }
    }
  } else { // mode 1: transposed output via LDS (reuses smem)
    __syncthreads();
    u16* YT = smem; // [128][72]
    #pragma unroll
    for (int ct = 0; ct < 8; ++ct) {
      float bn = bias[ct * 16 + lr];
      #pragma unroll
      for (int j = 0; j < 4; ++j)
        YT[(ct * 16 + lr) * 72 + 16 * w + 4 * lg + j] = f2bf(acc[ct][j] + bn);
    }
    __syncthreads();
    u16* o = (u16*)out;
    const int bI = rows0 >> 10, s0 = rows0 & 1023;
    #pragma unroll
    for (int i = 0; i < 4; ++i) {
      int u = tid + i * 256;          // [0,1024): n = u>>3, 8-elem chunk = u&7
      int n = u >> 3, ch = (u & 7) * 8;
      int4 v = *(const int4*)(YT + n * 72 + ch);
      *(int4*)(o + ((bI * 8 + (n >> 4)) * 16 + (n & 15)) * 1024 + s0 + ch) = v;
    }
  }
}

// ---------------------------------------------------------------------------
// Fused attention: per block = (b, h, 16 p-rows). 4 waves split S (256 each).
// pass1: QK^T (MFMA, K=16 zero-padded) + prev + gate -> raw_scores (global)
//        + rs stash (LDS bf16) + row max.
// pass2: e = exp(rs - max) in LDS, per-row denom.
// pass3: coalesced attn writes; PV MFMA with 1/den folded into output tile.
// ---------------------------------------------------------------------------
__global__ __launch_bounds__(256, 4)
void attn_kernel(const u16* __restrict__ qb, const u16* __restrict__ kb,
                 const u16* __restrict__ vtb, const float* __restrict__ prev,
                 const float* __restrict__ ch_gate,
                 float* __restrict__ rs_out, float* __restrict__ attn_out,
                 float* __restrict__ preout)
{
  __shared__ __attribute__((aligned(16))) u16 SRS[16][1032];
  __shared__ float rowred[4][16];
  __shared__ float Mrow[16];
  __shared__ float DenInv[16];
  __shared__ float OutBuf[4][16][20];

  const int bid = blockIdx.x;
  const int vb = (bid & 7) * 256 + (bid >> 3);  // XCD swizzle: batch b per XCD
  const int pt = vb & 31, h = (vb >> 5) & 7, b = vb >> 8;
  const int p0 = pt * 16, ptch = pt >> 2;       // predictor channel (p/64)
  const int tid = threadIdx.x, w = tid >> 6, l = tid & 63;
  const int lg = l >> 4, lr = l & 15;

  float gflag[8];
  #pragma unroll
  for (int j = 0; j < 8; ++j)
    gflag[j] = (ch_gate[ptch * 8 + j] >= 0.f) ? 1.f : 0.f;  // sigmoid>=0.5 <=> x>=0

  Frag aq;
  if (lg < 2) aq.i = *(const int4*)(qb + (((b * 8 + h) * 512 + p0 + lr) * 16 + 8 * lg));
  else        aq.i = make_int4(0, 0, 0, 0);

  const int base = ((b * 512 + p0) * 8 + h) * 1024;
  const u16* kbase = kb + (b * 8 + h) * 1024 * 16;
  const int sbase = w * 256;

  float mx[4] = {-1e30f, -1e30f, -1e30f, -1e30f};

  #pragma unroll 2
  for (int st = 0; st < 16; ++st) {
    const int s0 = sbase + st * 16;
    Frag bk;
    if (lg < 2) bk.i = *(const int4*)(kbase + (s0 + lr) * 16 + 8 * lg);
    else        bk.i = make_int4(0, 0, 0, 0);
    f32x4 zero = {0.f, 0.f, 0.f, 0.f};
    f32x4 d = __builtin_amdgcn_mfma_f32_16x16x32_bf16(aq.b, bk.b, zero, 0, 0, 0);
    const float g = gflag[s0 >> 7];
    const bool allowed = ((s0 >> 7) != ptch);
    #pragma unroll
    for (int j = 0; j < 4; ++j) {
      const int pl = 4 * lg + j;
      float pv = __builtin_nontemporal_load(prev + base + pl * 8192 + s0 + lr);
      float rs = (d[j] * 0.25f + pv) * g;
      __builtin_nontemporal_store(rs, rs_out + base + pl * 8192 + s0 + lr);
      SRS[pl][s0 + lr] = f2bf(rs);
      if (allowed) mx[j] = fmaxf(mx[j], rs);
    }
  }

  // row max: reduce across the 16 lanes sharing each row, then across waves
  #pragma unroll
  for (int off = 1; off < 16; off <<= 1) {
    #pragma unroll
    for (int j = 0; j < 4; ++j)
      mx[j] = fmaxf(mx[j], __shfl_xor(mx[j], off));
  }
  if (lr == 0) {
    #pragma unroll
    for (int j = 0; j < 4; ++j) rowred[w][4 * lg + j] = mx[j];
  }
  __syncthreads();
  if (tid < 16)
    Mrow[tid] = fmaxf(fmaxf(rowred[0][tid], rowred[1][tid]),
                      fmaxf(rowred[2][tid], rowred[3][tid]));
  __syncthreads();

  // pass 2: e = exp(rs - M) into SRS (bf16); per-row denom (one wave owns 4 rows)
  const int r = w * 4 + lg;
  const float mr = Mrow[r];
  float den = 0.f;
  #pragma unroll 2
  for (int it = 0; it < 16; ++it) {
    const int s = it * 64 + lr * 4;
    uint2* p = (uint2*)&SRS[r][s];
    if ((it >> 1) == ptch) {
      *p = make_uint2(0u, 0u);            // masked channel -> attn = 0
    } else {
      uint2 raw = *p;
      float f0 = bf2f(raw.x & 0xffffu);
      float f1 = bf2f(raw.x >> 16);
      float f2 = bf2f(raw.y & 0xffffu);
      float f3 = bf2f(raw.y >> 16);
      float e0 = __expf(f0 - mr), e1 = __expf(f1 - mr);
      float e2 = __expf(f2 - mr), e3 = __expf(f3 - mr);
      den += (e0 + e1) + (e2 + e3);
      uint2 pk;
      pk.x = (unsigned)f2bf(e0) | ((unsigned)f2bf(e1) << 16);
      pk.y = (unsigned)f2bf(e2) | ((unsigned)f2bf(e3) << 16);
      *p = pk;
    }
  }
  #pragma unroll
  for (int off = 1; off < 16; off <<= 1)
    den += __shfl_xor(den, off);
  if (lr == 0) DenInv[r] = 1.f / den;     // den >= 1 always (exp(0)=1 at the max)
  __syncthreads();

  // pass 3a: attn writes, 256B-contiguous per row per iteration
  {
    const float invd = DenInv[r];
    float* arow = attn_out + base + r * 8192;
    #pragma unroll 2
    for (int it = 0; it < 16; ++it) {
      const int s = it * 64 + lr * 4;
      f32x4 o;
      if ((it >> 1) == ptch) {
        o = (f32x4){0.f, 0.f, 0.f, 0.f};
      } else {
        uint2 raw = *(const uint2*)&SRS[r][s];
        o[0] = bf2f(raw.x & 0xffffu) * invd;
        o[1] = bf2f(raw.x >> 16) * invd;
        o[2] = bf2f(raw.y & 0xffffu) * invd;
        o[3] = bf2f(raw.y >> 16) * invd;
      }
      __builtin_nontemporal_store(o, (f32x4*)(arow + s));
    }
  }

  // pass 3b: PV (unnormalized e; 1/den folded into output rows)
  f32x4 acc = {0.f, 0.f, 0.f, 0.f};
  const u16* vbase = vtb + ((b * 8 + h) * 16 + lr) * 1024;
  #pragma unroll
  for (int kc = 0; kc < 8; ++kc) {
    Frag pa, bv;
    pa.i = *(const int4*)(&SRS[lr][sbase + kc * 32 + 8 * lg]);
    bv.i = *(const int4*)(vbase + sbase + kc * 32 + 8 * lg);
    acc = __builtin_amdgcn_mfma_f32_16x16x32_bf16(pa.b, bv.b, acc, 0, 0, 0);
  }
  #pragma unroll
  for (int j = 0; j < 4; ++j) OutBuf[w][4 * lg + j][lr] = acc[j];
  __syncthreads();
  {
    const int pr = tid >> 4, dd = tid & 15;
    float o = (OutBuf[0][pr][dd] + OutBuf[1][pr][dd] +
               OutBuf[2][pr][dd] + OutBuf[3][pr][dd]) * DenInv[pr];
    preout[((b * 512 + p0 + pr) * 8 + h) * 16 + dd] = o;
  }
}

// ---------------------------------------------------------------------------
extern "C" void kernel_launch(void* const* d_in, const int* in_sizes, int n_in,
                              void* d_out, int out_size, void* d_ws, size_t ws_size,
                              hipStream_t stream)
{
  (void)in_sizes; (void)n_in; (void)out_size; (void)ws_size;
  const float* Q       = (const float*)d_in[0];
  const float* K       = (const float*)d_in[1];
  const float* V       = (const float*)d_in[2];
  const float* prev    = (const float*)d_in[3];
  // d_in[4] = attn_mask (derived analytically, unused)
  const float* Wq      = (const float*)d_in[5];
  const float* bq      = (const float*)d_in[6];
  const float* Wk      = (const float*)d_in[7];
  const float* bk      = (const float*)d_in[8];
  const float* Wv      = (const float*)d_in[9];
  const float* bv      = (const float*)d_in[10];
  const float* Wo      = (const float*)d_in[11];
  const float* bo      = (const float*)d_in[12];
  const float* ch_gate = (const float*)d_in[13];

  // workspace layout (7 MB total)
  u16*   qb     = (u16*)d_ws;                        // 524288 bf16 (1 MB)
  u16*   kb     = qb + 524288;                       // 1048576 bf16 (2 MB)
  u16*   vtb    = kb + 1048576;                      // 1048576 bf16 (2 MB)
  float* preout = (float*)((char*)d_ws + 5242880);   // 524288 fp32 (2 MB)

  float* outp     = (float*)d_out;          // (B,P,128)
  float* attn_out = outp + 524288;          // (B,P,H,S)
  float* rs_out   = outp + 34078720;        // (B,P,H,S)

  proj_kernel<<<64,  256, 0, stream>>>(Q, Wq, bq, qb,  0,  9);
  proj_kernel<<<128, 256, 0, stream>>>(K, Wk, bk, kb,  0, 10);
  proj_kernel<<<128, 256, 0, stream>>>(V, Wv, bv, vtb, 1, 10);
  attn_kernel<<<2048, 256, 0, stream>>>(qb, kb, vtb, prev, ch_gate,
                                        rs_out, attn_out, preout);
  proj_kernel<<<64,  256, 0, stream>>>(preout, Wo, bo, outp, 2,  9);
}

// Round 2
// 141.362 us; speedup vs baseline: 1.0971x; 1.0971x over previous
//
#include <hip/hip_runtime.h>
#include <hip/hip_bf16.h>

typedef unsigned short u16;
typedef float f32x4 __attribute__((ext_vector_type(4)));
typedef __bf16 bf16x8 __attribute__((ext_vector_type(8)));

union Frag { int4 i; bf16x8 b; };

__device__ inline u16 f2bf(float f) {
  union { float f; unsigned u; } v; v.f = f;
  unsigned r = v.u + 0x7FFFu + ((v.u >> 16) & 1u);
  return (u16)(r >> 16);
}
__device__ inline float bf2f(unsigned b) {
  union { unsigned u; float f; } v; v.u = b << 16;
  return v.f;
}

// ---------------------------------------------------------------------------
// Projection GEMM body: Y = X @ W.T + bias (X: rows x 128 fp32, W: 128x128)
// mode 0: out bf16 head-major  [b][h][row][16]
// mode 1: out bf16 transposed  [b][h][16][1024]  (V)
// mode 2: out fp32 row-major   [row][128]        (out-proj)
// 64 rows per block, 256 threads (4 waves x 16 rows each).
// ---------------------------------------------------------------------------
__device__ __forceinline__
void proj_body(u16* __restrict__ smem,
               const float* __restrict__ X, const float* __restrict__ W,
               const float* __restrict__ bias, void* __restrict__ out,
               int mode, int innerShift, int rows0)
{
  u16* XL = smem;              // [64][136]
  u16* WL = smem + 64 * 136;   // [128][136]

  const int tid = threadIdx.x;
  const int w = tid >> 6, l = tid & 63, lg = l >> 4, lr = l & 15;

  #pragma unroll
  for (int i = 0; i < 8; ++i) {
    int u = tid + i * 256;
    int rr = u >> 5, c4 = (u & 31) * 4;
    const float4 xv = *(const float4*)(X + (rows0 + rr) * 128 + c4);
    uint2 p;
    p.x = (unsigned)f2bf(xv.x) | ((unsigned)f2bf(xv.y) << 16);
    p.y = (unsigned)f2bf(xv.z) | ((unsigned)f2bf(xv.w) << 16);
    *(uint2*)(XL + rr * 136 + c4) = p;
  }
  #pragma unroll
  for (int i = 0; i < 16; ++i) {
    int u = tid + i * 256;
    int rr = u >> 5, c4 = (u & 31) * 4;
    const float4 xv = *(const float4*)(W + rr * 128 + c4);
    uint2 p;
    p.x = (unsigned)f2bf(xv.x) | ((unsigned)f2bf(xv.y) << 16);
    p.y = (unsigned)f2bf(xv.z) | ((unsigned)f2bf(xv.w) << 16);
    *(uint2*)(WL + rr * 136 + c4) = p;
  }
  __syncthreads();

  Frag a[4];
  #pragma unroll
  for (int kc = 0; kc < 4; ++kc)
    a[kc].i = *(const int4*)(XL + (16 * w + lr) * 136 + kc * 32 + 8 * lg);

  f32x4 acc[8];
  #pragma unroll
  for (int ct = 0; ct < 8; ++ct) {
    f32x4 c = {0.f, 0.f, 0.f, 0.f};
    #pragma unroll
    for (int kc = 0; kc < 4; ++kc) {
      Frag bw;
      bw.i = *(const int4*)(WL + (ct * 16 + lr) * 136 + kc * 32 + 8 * lg);
      c = __builtin_amdgcn_mfma_f32_16x16x32_bf16(a[kc].b, bw.b, c, 0, 0, 0);
    }
    acc[ct] = c;
  }

  if (mode == 2) {
    float* o = (float*)out;
    #pragma unroll
    for (int ct = 0; ct < 8; ++ct) {
      float bn = bias[ct * 16 + lr];
      #pragma unroll
      for (int j = 0; j < 4; ++j) {
        int row = rows0 + 16 * w + 4 * lg + j;
        o[row * 128 + ct * 16 + lr] = acc[ct][j] + bn;
      }
    }
  } else if (mode == 0) {
    u16* o = (u16*)out;
    const int innerMask = (1 << innerShift) - 1;
    #pragma unroll
    for (int ct = 0; ct < 8; ++ct) {
      float bn = bias[ct * 16 + lr];
      #pragma unroll
      for (int j = 0; j < 4; ++j) {
        int row = rows0 + 16 * w + 4 * lg + j;
        int bI = row >> innerShift, r = row & innerMask;
        o[(((bI * 8 + ct) << innerShift) + r) * 16 + lr] = f2bf(acc[ct][j] + bn);
      }
    }
  } else { // mode 1: transposed output via LDS
    __syncthreads();
    u16* YT = smem; // [128][72]
    #pragma unroll
    for (int ct = 0; ct < 8; ++ct) {
      float bn = bias[ct * 16 + lr];
      #pragma unroll
      for (int j = 0; j < 4; ++j)
        YT[(ct * 16 + lr) * 72 + 16 * w + 4 * lg + j] = f2bf(acc[ct][j] + bn);
    }
    __syncthreads();
    u16* o = (u16*)out;
    const int bI = rows0 >> 10, s0 = rows0 & 1023;
    #pragma unroll
    for (int i = 0; i < 4; ++i) {
      int u = tid + i * 256;
      int n = u >> 3, ch = (u & 7) * 8;
      int4 v = *(const int4*)(YT + n * 72 + ch);
      *(int4*)(o + ((bI * 8 + (n >> 4)) * 16 + (n & 15)) * 1024 + s0 + ch) = v;
    }
  }
}

__global__ __launch_bounds__(256, 2)
void proj_qkv(const float* __restrict__ Q, const float* __restrict__ K,
              const float* __restrict__ V,
              const float* __restrict__ Wq, const float* __restrict__ bq,
              const float* __restrict__ Wk, const float* __restrict__ bk,
              const float* __restrict__ Wv, const float* __restrict__ bv,
              u16* __restrict__ qb, u16* __restrict__ kb, u16* __restrict__ vtb)
{
  __shared__ __attribute__((aligned(16))) u16 smem[26112];
  const int bid = blockIdx.x;
  if (bid < 64)       proj_body(smem, Q, Wq, bq, qb,  0,  9, bid * 64);
  else if (bid < 192) proj_body(smem, K, Wk, bk, kb,  0, 10, (bid - 64) * 64);
  else                proj_body(smem, V, Wv, bv, vtb, 1, 10, (bid - 192) * 64);
}

__global__ __launch_bounds__(256, 2)
void proj_out(const float* __restrict__ X, const float* __restrict__ W,
              const float* __restrict__ bias, float* __restrict__ out)
{
  __shared__ __attribute__((aligned(16))) u16 smem[26112];
  proj_body(smem, X, W, bias, out, 2, 9, blockIdx.x * 64);
}

// ---------------------------------------------------------------------------
// Fused attention. Block = (b, h, 16 p-rows); 4 waves.
// Phase A: QK^T MFMAs -> scores (bf16, *scale) in LDS. Waves split S.
// Phase B: waves own 4 rows each; float4-stream prev, rs fp32 -> rs_out,
//          rs bf16 -> LDS, in-register row max.
// Phase B2: e = exp(rs-M) in LDS, denom via shuffle.
// Phase B3: float4 attn writes.  PV MFMA; 1/den folded at output.
// ---------------------------------------------------------------------------
__global__ __launch_bounds__(256, 4)
void attn_kernel(const u16* __restrict__ qb, const u16* __restrict__ kb,
                 const u16* __restrict__ vtb, const float* __restrict__ prev,
                 const float* __restrict__ ch_gate,
                 float* __restrict__ rs_out, float* __restrict__ attn_out,
                 float* __restrict__ preout)
{
  __shared__ __attribute__((aligned(16))) u16 SRS[16][1032];
  __shared__ float DenInv[16];
  __shared__ float OutBuf[4][16][20];

  const int bid = blockIdx.x;
  const int vb = (bid & 7) * 256 + (bid >> 3);  // XCD swizzle: one batch per XCD
  const int pt = vb & 31, h = (vb >> 5) & 7, b = vb >> 8;
  const int p0 = pt * 16, ptch = pt >> 2;       // predictor channel
  const int tid = threadIdx.x, w = tid >> 6, l = tid & 63;
  const int lg = l >> 4, lr = l & 15;

  float gflag[8];
  #pragma unroll
  for (int j = 0; j < 8; ++j)
    gflag[j] = (ch_gate[ptch * 8 + j] >= 0.f) ? 1.f : 0.f;

  // ---- Phase A: QK^T scores -> LDS (bf16) ----
  Frag aq;
  if (lg < 2) aq.i = *(const int4*)(qb + (((b * 8 + h) * 512 + p0 + lr) * 16 + 8 * lg));
  else        aq.i = make_int4(0, 0, 0, 0);

  const u16* kbase = kb + (b * 8 + h) * 1024 * 16;
  const int sbase = w * 256;

  #pragma unroll 4
  for (int st = 0; st < 16; ++st) {
    const int s0 = sbase + st * 16;
    Frag bk;
    if (lg < 2) bk.i = *(const int4*)(kbase + (s0 + lr) * 16 + 8 * lg);
    else        bk.i = make_int4(0, 0, 0, 0);
    f32x4 zero = {0.f, 0.f, 0.f, 0.f};
    f32x4 d = __builtin_amdgcn_mfma_f32_16x16x32_bf16(aq.b, bk.b, zero, 0, 0, 0);
    #pragma unroll
    for (int j = 0; j < 4; ++j)
      SRS[4 * lg + j][s0 + lr] = f2bf(d[j] * 0.25f);
  }
  __syncthreads();

  // ---- Phase B: stream prev; rs = (sc + prev) * g ----
  const int r = 4 * w + lg;                       // wave owns rows 4w..4w+3
  const int base = ((b * 512 + p0) * 8 + h) * 1024;
  const float* prow = prev + base + r * 8192;
  float* rsrow = rs_out + base + r * 8192;
  float mx = -1e30f;

  #pragma unroll 4
  for (int it = 0; it < 16; ++it) {
    const int s = it * 64 + lr * 4;
    const float g = gflag[it >> 1];
    f32x4 pv = __builtin_nontemporal_load((const f32x4*)(prow + s));
    uint2 sc = *(const uint2*)&SRS[r][s];
    f32x4 rs;
    rs[0] = (bf2f(sc.x & 0xffffu) + pv[0]) * g;
    rs[1] = (bf2f(sc.x >> 16)     + pv[1]) * g;
    rs[2] = (bf2f(sc.y & 0xffffu) + pv[2]) * g;
    rs[3] = (bf2f(sc.y >> 16)     + pv[3]) * g;
    __builtin_nontemporal_store(rs, (f32x4*)(rsrow + s));
    uint2 pk;
    pk.x = (unsigned)f2bf(rs[0]) | ((unsigned)f2bf(rs[1]) << 16);
    pk.y = (unsigned)f2bf(rs[2]) | ((unsigned)f2bf(rs[3]) << 16);
    *(uint2*)&SRS[r][s] = pk;
    if ((it >> 1) != ptch) {
      mx = fmaxf(mx, fmaxf(fmaxf(rs[0], rs[1]), fmaxf(rs[2], rs[3])));
    }
  }
  #pragma unroll
  for (int off = 1; off < 16; off <<= 1)
    mx = fmaxf(mx, __shfl_xor(mx, off));

  // ---- Phase B2: e = exp(rs - mx), denom ----
  float den = 0.f;
  #pragma unroll 4
  for (int it = 0; it < 16; ++it) {
    const int s = it * 64 + lr * 4;
    uint2* p = (uint2*)&SRS[r][s];
    if ((it >> 1) == ptch) {
      *p = make_uint2(0u, 0u);
    } else {
      uint2 raw = *p;
      float e0 = __expf(bf2f(raw.x & 0xffffu) - mx);
      float e1 = __expf(bf2f(raw.x >> 16)     - mx);
      float e2 = __expf(bf2f(raw.y & 0xffffu) - mx);
      float e3 = __expf(bf2f(raw.y >> 16)     - mx);
      den += (e0 + e1) + (e2 + e3);
      uint2 pk;
      pk.x = (unsigned)f2bf(e0) | ((unsigned)f2bf(e1) << 16);
      pk.y = (unsigned)f2bf(e2) | ((unsigned)f2bf(e3) << 16);
      *p = pk;
    }
  }
  #pragma unroll
  for (int off = 1; off < 16; off <<= 1)
    den += __shfl_xor(den, off);
  const float invd = 1.f / den;                  // den >= 1 (exp(0) at max)
  if (lr == 0) DenInv[r] = invd;
  __syncthreads();                               // e visible to all waves (PV)

  // ---- Phase B3: attn = e * invd, float4 nt stores ----
  {
    float* arow = attn_out + base + r * 8192;
    #pragma unroll 4
    for (int it = 0; it < 16; ++it) {
      const int s = it * 64 + lr * 4;
      f32x4 o;
      if ((it >> 1) == ptch) {
        o = (f32x4){0.f, 0.f, 0.f, 0.f};
      } else {
        uint2 raw = *(const uint2*)&SRS[r][s];
        o[0] = bf2f(raw.x & 0xffffu) * invd;
        o[1] = bf2f(raw.x >> 16)     * invd;
        o[2] = bf2f(raw.y & 0xffffu) * invd;
        o[3] = bf2f(raw.y >> 16)     * invd;
      }
      __builtin_nontemporal_store(o, (f32x4*)(arow + s));
    }
  }

  // ---- PV: acc = sum_s e[p][s] * v[s][d], 1/den folded at output ----
  f32x4 acc = {0.f, 0.f, 0.f, 0.f};
  const u16* vbase = vtb + ((b * 8 + h) * 16 + lr) * 1024;
  #pragma unroll
  for (int kc = 0; kc < 8; ++kc) {
    Frag pa, bv;
    pa.i = *(const int4*)(&SRS[lr][sbase + kc * 32 + 8 * lg]);
    bv.i = *(const int4*)(vbase + sbase + kc * 32 + 8 * lg);
    acc = __builtin_amdgcn_mfma_f32_16x16x32_bf16(pa.b, bv.b, acc, 0, 0, 0);
  }
  #pragma unroll
  for (int j = 0; j < 4; ++j) OutBuf[w][4 * lg + j][lr] = acc[j];
  __syncthreads();
  {
    const int pr = tid >> 4, dd = tid & 15;
    float o = (OutBuf[0][pr][dd] + OutBuf[1][pr][dd] +
               OutBuf[2][pr][dd] + OutBuf[3][pr][dd]) * DenInv[pr];
    preout[((b * 512 + p0 + pr) * 8 + h) * 16 + dd] = o;
  }
}

// ---------------------------------------------------------------------------
extern "C" void kernel_launch(void* const* d_in, const int* in_sizes, int n_in,
                              void* d_out, int out_size, void* d_ws, size_t ws_size,
                              hipStream_t stream)
{
  (void)in_sizes; (void)n_in; (void)out_size; (void)ws_size;
  const float* Q       = (const float*)d_in[0];
  const float* K       = (const float*)d_in[1];
  const float* V       = (const float*)d_in[2];
  const float* prev    = (const float*)d_in[3];
  const float* Wq      = (const float*)d_in[5];
  const float* bq      = (const float*)d_in[6];
  const float* Wk      = (const float*)d_in[7];
  const float* bk      = (const float*)d_in[8];
  const float* Wv      = (const float*)d_in[9];
  const float* bv      = (const float*)d_in[10];
  const float* Wo      = (const float*)d_in[11];
  const float* bo      = (const float*)d_in[12];
  const float* ch_gate = (const float*)d_in[13];

  u16*   qb     = (u16*)d_ws;                        // 1 MB bf16
  u16*   kb     = qb + 524288;                       // 2 MB bf16
  u16*   vtb    = kb + 1048576;                      // 2 MB bf16
  float* preout = (float*)((char*)d_ws + 5242880);   // 2 MB fp32

  float* outp     = (float*)d_out;          // (B,P,128)
  float* attn_out = outp + 524288;          // (B,P,H,S)
  float* rs_out   = outp + 34078720;        // (B,P,H,S)

  proj_qkv<<<320, 256, 0, stream>>>(Q, K, V, Wq, bq, Wk, bk, Wv, bv,
                                    qb, kb, vtb);
  attn_kernel<<<2048, 256, 0, stream>>>(qb, kb, vtb, prev, ch_gate,
                                        rs_out, attn_out, preout);
  proj_out<<<64, 256, 0, stream>>>(preout, Wo, bo, outp);
}

// Round 3
// 117.646 us; speedup vs baseline: 1.3182x; 1.2016x over previous
//
#include <hip/hip_runtime.h>
#include <hip/hip_bf16.h>

typedef unsigned short u16;
typedef float f32x4 __attribute__((ext_vector_type(4)));
typedef __bf16 bf16x8 __attribute__((ext_vector_type(8)));
typedef _Float16 f16x8 __attribute__((ext_vector_type(8)));

union Frag { int4 i; bf16x8 b; f16x8 h; };

__device__ inline u16 f2bf(float f) {
  union { float f; unsigned u; } v; v.f = f;
  unsigned r = v.u + 0x7FFFu + ((v.u >> 16) & 1u);
  return (u16)(r >> 16);
}
__device__ inline float bf2f(unsigned b) {
  union { unsigned u; float f; } v; v.u = b << 16;
  return v.f;
}
__device__ inline float trunc_bf(float x) {  // fp32 -> nearest-lower bf16 (in fp32)
  return __builtin_bit_cast(float, __builtin_bit_cast(unsigned, x) & 0xFFFF0000u);
}
__device__ inline unsigned packhi(float a, float b) { // {bf16(a), bf16(b)} packed
  return __builtin_amdgcn_perm(__builtin_bit_cast(unsigned, b),
                               __builtin_bit_cast(unsigned, a), 0x07060302u);
}

// ---------------------------------------------------------------------------
// Projection GEMM body: Y = X @ W.T + bias (X: rows x 128 fp32, W: 128x128)
// mode 0: out f16  head-major  [b][h][row][16]   (q, k)
// mode 1: out bf16 transposed  [b][h][16][1024]  (V)
// mode 2: out fp32 row-major   [row][128]        (out-proj)
// ---------------------------------------------------------------------------
__device__ __forceinline__
void proj_body(u16* __restrict__ smem,
               const float* __restrict__ X, const float* __restrict__ W,
               const float* __restrict__ bias, void* __restrict__ out,
               int mode, int innerShift, int rows0)
{
  u16* XL = smem;              // [64][136]
  u16* WL = smem + 64 * 136;   // [128][136]

  const int tid = threadIdx.x;
  const int w = tid >> 6, l = tid & 63, lg = l >> 4, lr = l & 15;

  #pragma unroll
  for (int i = 0; i < 8; ++i) {
    int u = tid + i * 256;
    int rr = u >> 5, c4 = (u & 31) * 4;
    const float4 xv = *(const float4*)(X + (rows0 + rr) * 128 + c4);
    uint2 p;
    p.x = (unsigned)f2bf(xv.x) | ((unsigned)f2bf(xv.y) << 16);
    p.y = (unsigned)f2bf(xv.z) | ((unsigned)f2bf(xv.w) << 16);
    *(uint2*)(XL + rr * 136 + c4) = p;
  }
  #pragma unroll
  for (int i = 0; i < 16; ++i) {
    int u = tid + i * 256;
    int rr = u >> 5, c4 = (u & 31) * 4;
    const float4 xv = *(const float4*)(W + rr * 128 + c4);
    uint2 p;
    p.x = (unsigned)f2bf(xv.x) | ((unsigned)f2bf(xv.y) << 16);
    p.y = (unsigned)f2bf(xv.z) | ((unsigned)f2bf(xv.w) << 16);
    *(uint2*)(WL + rr * 136 + c4) = p;
  }
  __syncthreads();

  Frag a[4];
  #pragma unroll
  for (int kc = 0; kc < 4; ++kc)
    a[kc].i = *(const int4*)(XL + (16 * w + lr) * 136 + kc * 32 + 8 * lg);

  f32x4 acc[8];
  #pragma unroll
  for (int ct = 0; ct < 8; ++ct) {
    f32x4 c = {0.f, 0.f, 0.f, 0.f};
    #pragma unroll
    for (int kc = 0; kc < 4; ++kc) {
      Frag bw;
      bw.i = *(const int4*)(WL + (ct * 16 + lr) * 136 + kc * 32 + 8 * lg);
      c = __builtin_amdgcn_mfma_f32_16x16x32_bf16(a[kc].b, bw.b, c, 0, 0, 0);
    }
    acc[ct] = c;
  }

  if (mode == 2) {
    float* o = (float*)out;
    #pragma unroll
    for (int ct = 0; ct < 8; ++ct) {
      float bn = bias[ct * 16 + lr];
      #pragma unroll
      for (int j = 0; j < 4; ++j) {
        int row = rows0 + 16 * w + 4 * lg + j;
        o[row * 128 + ct * 16 + lr] = acc[ct][j] + bn;
      }
    }
  } else if (mode == 0) {  // f16 head-major (q, k)
    u16* o = (u16*)out;
    const int innerMask = (1 << innerShift) - 1;
    #pragma unroll
    for (int ct = 0; ct < 8; ++ct) {
      float bn = bias[ct * 16 + lr];
      #pragma unroll
      for (int j = 0; j < 4; ++j) {
        int row = rows0 + 16 * w + 4 * lg + j;
        int bI = row >> innerShift, r = row & innerMask;
        o[(((bI * 8 + ct) << innerShift) + r) * 16 + lr] =
            __builtin_bit_cast(u16, (_Float16)(acc[ct][j] + bn));
      }
    }
  } else { // mode 1: bf16 transposed via LDS
    __syncthreads();
    u16* YT = smem; // [128][72]
    #pragma unroll
    for (int ct = 0; ct < 8; ++ct) {
      float bn = bias[ct * 16 + lr];
      #pragma unroll
      for (int j = 0; j < 4; ++j)
        YT[(ct * 16 + lr) * 72 + 16 * w + 4 * lg + j] = f2bf(acc[ct][j] + bn);
    }
    __syncthreads();
    u16* o = (u16*)out;
    const int bI = rows0 >> 10, s0 = rows0 & 1023;
    #pragma unroll
    for (int i = 0; i < 4; ++i) {
      int u = tid + i * 256;
      int n = u >> 3, ch = (u & 7) * 8;
      int4 v = *(const int4*)(YT + n * 72 + ch);
      *(int4*)(o + ((bI * 8 + (n >> 4)) * 16 + (n & 15)) * 1024 + s0 + ch) = v;
    }
  }
}

__global__ __launch_bounds__(256, 2)
void proj_qkv(const float* __restrict__ Q, const float* __restrict__ K,
              const float* __restrict__ V,
              const float* __restrict__ Wq, const float* __restrict__ bq,
              const float* __restrict__ Wk, const float* __restrict__ bk,
              const float* __restrict__ Wv, const float* __restrict__ bv,
              u16* __restrict__ qb, u16* __restrict__ kb, u16* __restrict__ vtb)
{
  __shared__ __attribute__((aligned(16))) u16 smem[26112];
  const int bid = blockIdx.x;
  if (bid < 64)       proj_body(smem, Q, Wq, bq, qb,  0,  9, bid * 64);
  else if (bid < 192) proj_body(smem, K, Wk, bk, kb,  0, 10, (bid - 64) * 64);
  else                proj_body(smem, V, Wv, bv, vtb, 1, 10, (bid - 192) * 64);
}

__global__ __launch_bounds__(256, 2)
void proj_out(const float* __restrict__ X, const float* __restrict__ W,
              const float* __restrict__ bias, float* __restrict__ out)
{
  __shared__ __attribute__((aligned(16))) u16 smem[26112];
  proj_body(smem, X, W, bias, out, 2, 9, blockIdx.x * 64);
}

// ---------------------------------------------------------------------------
// Fused attention. Block = (b, h, 16 p-rows); 4 waves.
// Phase A: QK^T (f16 MFMA) -> scores f16 in LDS (gated-on channels only).
// Phase B: stream prev (prefetch depth 4 issued before A); rs fp32 -> rs_out;
//          e = exp(rs) bf16-truncated -> LDS; online den (max-free softmax).
//          Gated-off channels: zero rs, e = 1, no loads, no exp.
// Phase B3: attn = e * invd, float4 nt stores; PV MFMA (bf16).
// ---------------------------------------------------------------------------
__global__ __launch_bounds__(256, 4)
void attn_kernel(const u16* __restrict__ qb, const u16* __restrict__ kb,
                 const u16* __restrict__ vtb, const float* __restrict__ prev,
                 const float* __restrict__ ch_gate,
                 float* __restrict__ rs_out, float* __restrict__ attn_out,
                 float* __restrict__ preout)
{
  __shared__ __attribute__((aligned(16))) u16 SRS[16][1032];
  __shared__ float DenInv[16];
  __shared__ float OutBuf[4][16][20];

  const int bid = blockIdx.x;
  const int vb = (bid & 7) * 256 + (bid >> 3);  // XCD swizzle: one batch per XCD
  const int pt = vb & 31, h = (vb >> 5) & 7, b = vb >> 8;
  const int p0 = pt * 16, ptch = pt >> 2;       // predictor channel
  const int tid = threadIdx.x, w = tid >> 6, l = tid & 63;
  const int lg = l >> 4, lr = l & 15;

  // gate bits for this predictor channel (sigmoid(x)>=0.5 <=> x>=0), scalar
  unsigned gbits = 0u;
  #pragma unroll
  for (int j = 0; j < 8; ++j)
    if (ch_gate[ptch * 8 + j] >= 0.f) gbits |= (1u << j);
  gbits = __builtin_amdgcn_readfirstlane(gbits);

  const int r = 4 * w + lg;                      // row this thread streams in B
  const int base = ((b * 512 + p0) * 8 + h) * 1024;
  const float* prow = prev + base + r * 8192;

  // prefetch first 4 chunks of prev (covers phase A's HBM idle)
  f32x4 pf0 = __builtin_nontemporal_load((const f32x4*)(prow +   0 + lr * 4));
  f32x4 pf1 = __builtin_nontemporal_load((const f32x4*)(prow +  64 + lr * 4));
  f32x4 pf2 = __builtin_nontemporal_load((const f32x4*)(prow + 128 + lr * 4));
  f32x4 pf3 = __builtin_nontemporal_load((const f32x4*)(prow + 192 + lr * 4));

  // ---- Phase A: QK^T scores (f16) -> LDS, gated-on channels only ----
  Frag aq;
  if (lg < 2) aq.i = *(const int4*)(qb + (((b * 8 + h) * 512 + p0 + lr) * 16 + 8 * lg));
  else        aq.i = make_int4(0, 0, 0, 0);

  const u16* kbase = kb + (b * 8 + h) * 1024 * 16;
  const int sbase = w * 256;

  #pragma unroll 2
  for (int st = 0; st < 16; ++st) {
    const int s0 = sbase + st * 16;
    if (!((gbits >> (s0 >> 7)) & 1u)) continue;
    Frag bk;
    if (lg < 2) bk.i = *(const int4*)(kbase + (s0 + lr) * 16 + 8 * lg);
    else        bk.i = make_int4(0, 0, 0, 0);
    f32x4 zero = {0.f, 0.f, 0.f, 0.f};
    f32x4 d = __builtin_amdgcn_mfma_f32_16x16x32_f16(aq.h, bk.h, zero, 0, 0, 0);
    #pragma unroll
    for (int j = 0; j < 4; ++j)
      SRS[4 * lg + j][s0 + lr] = __builtin_bit_cast(u16, (_Float16)(d[j] * 0.25f));
  }
  __syncthreads();

  // ---- Phase B: stream prev; rs -> global; e = exp(rs) -> LDS; online den ----
  float* rsrow = rs_out + base + r * 8192;
  const f32x4 zf = {0.f, 0.f, 0.f, 0.f};
  float den = 0.f;

  #pragma unroll
  for (int it = 0; it < 16; ++it) {
    const int s = it * 64 + lr * 4;
    const int ch = it >> 1;
    const bool msk = (ch == ptch);
    if ((gbits >> ch) & 1u) {
      f32x4 pv;
      if      (it == 0) pv = pf0;
      else if (it == 1) pv = pf1;
      else if (it == 2) pv = pf2;
      else if (it == 3) pv = pf3;
      else pv = __builtin_nontemporal_load((const f32x4*)(prow + s));
      union { uint2 u; _Float16 hh[4]; } sc;
      sc.u = *(const uint2*)&SRS[r][s];
      f32x4 rs;
      rs[0] = (float)sc.hh[0] + pv[0];
      rs[1] = (float)sc.hh[1] + pv[1];
      rs[2] = (float)sc.hh[2] + pv[2];
      rs[3] = (float)sc.hh[3] + pv[3];
      __builtin_nontemporal_store(rs, (f32x4*)(rsrow + s));
      if (msk) {
        *(uint2*)&SRS[r][s] = make_uint2(0u, 0u);
      } else {
        float e0 = trunc_bf(__expf(rs[0]));
        float e1 = trunc_bf(__expf(rs[1]));
        float e2 = trunc_bf(__expf(rs[2]));
        float e3 = trunc_bf(__expf(rs[3]));
        den += (e0 + e1) + (e2 + e3);
        uint2 pk;
        pk.x = packhi(e0, e1);
        pk.y = packhi(e2, e3);
        *(uint2*)&SRS[r][s] = pk;
      }
    } else {
      __builtin_nontemporal_store(zf, (f32x4*)(rsrow + s));
      if (msk) *(uint2*)&SRS[r][s] = make_uint2(0u, 0u);
      else   { *(uint2*)&SRS[r][s] = make_uint2(0x3F803F80u, 0x3F803F80u); den += 4.f; }
    }
  }

  #pragma unroll
  for (int off = 1; off < 16; off <<= 1)
    den += __shfl_xor(den, off);
  const float invd = 1.f / den;
  if (lr == 0) DenInv[r] = invd;
  __syncthreads();                               // e visible to all waves (PV)

  // ---- Phase B3: attn = e * invd ----
  {
    float* arow = attn_out + base + r * 8192;
    #pragma unroll
    for (int it = 0; it < 16; ++it) {
      const int s = it * 64 + lr * 4;
      const int ch = it >> 1;
      f32x4 o;
      if (ch == ptch) {
        o = zf;
      } else if (!((gbits >> ch) & 1u)) {
        o = (f32x4){invd, invd, invd, invd};
      } else {
        uint2 raw = *(const uint2*)&SRS[r][s];
        o[0] = bf2f(raw.x & 0xffffu) * invd;
        o[1] = bf2f(raw.x >> 16)     * invd;
        o[2] = bf2f(raw.y & 0xffffu) * invd;
        o[3] = bf2f(raw.y >> 16)     * invd;
      }
      __builtin_nontemporal_store(o, (f32x4*)(arow + s));
    }
  }

  // ---- PV: acc = sum_s e[p][s] * v[s][d], 1/den folded at output ----
  f32x4 acc = {0.f, 0.f, 0.f, 0.f};
  const u16* vbase = vtb + ((b * 8 + h) * 16 + lr) * 1024;
  #pragma unroll
  for (int kc = 0; kc < 8; ++kc) {
    Frag pa, bv;
    pa.i = *(const int4*)(&SRS[lr][sbase + kc * 32 + 8 * lg]);
    bv.i = *(const int4*)(vbase + sbase + kc * 32 + 8 * lg);
    acc = __builtin_amdgcn_mfma_f32_16x16x32_bf16(pa.b, bv.b, acc, 0, 0, 0);
  }
  #pragma unroll
  for (int j = 0; j < 4; ++j) OutBuf[w][4 * lg + j][lr] = acc[j];
  __syncthreads();
  {
    const int pr = tid >> 4, dd = tid & 15;
    float o = (OutBuf[0][pr][dd] + OutBuf[1][pr][dd] +
               OutBuf[2][pr][dd] + OutBuf[3][pr][dd]) * DenInv[pr];
    preout[((b * 512 + p0 + pr) * 8 + h) * 16 + dd] = o;
  }
}

// ---------------------------------------------------------------------------
extern "C" void kernel_launch(void* const* d_in, const int* in_sizes, int n_in,
                              void* d_out, int out_size, void* d_ws, size_t ws_size,
                              hipStream_t stream)
{
  (void)in_sizes; (void)n_in; (void)out_size; (void)ws_size;
  const float* Q       = (const float*)d_in[0];
  const float* K       = (const float*)d_in[1];
  const float* V       = (const float*)d_in[2];
  const float* prev    = (const float*)d_in[3];
  const float* Wq      = (const float*)d_in[5];
  const float* bq      = (const float*)d_in[6];
  const float* Wk      = (const float*)d_in[7];
  const float* bk      = (const float*)d_in[8];
  const float* Wv      = (const float*)d_in[9];
  const float* bv      = (const float*)d_in[10];
  const float* Wo      = (const float*)d_in[11];
  const float* bo      = (const float*)d_in[12];
  const float* ch_gate = (const float*)d_in[13];

  u16*   qb     = (u16*)d_ws;                        // 1 MB f16
  u16*   kb     = qb + 524288;                       // 2 MB f16
  u16*   vtb    = kb + 1048576;                      // 2 MB bf16
  float* preout = (float*)((char*)d_ws + 5242880);   // 2 MB fp32

  float* outp     = (float*)d_out;          // (B,P,128)
  float* attn_out = outp + 524288;          // (B,P,H,S)
  float* rs_out   = outp + 34078720;        // (B,P,H,S)

  proj_qkv<<<320, 256, 0, stream>>>(Q, K, V, Wq, bq, Wk, bk, Wv, bv,
                                    qb, kb, vtb);
  attn_kernel<<<2048, 256, 0, stream>>>(qb, kb, vtb, prev, ch_gate,
                                        rs_out, attn_out, preout);
  proj_out<<<64, 256, 0, stream>>>(preout, Wo, bo, outp);
}

// Round 4
// 111.257 us; speedup vs baseline: 1.3939x; 1.0574x over previous
//
#include <hip/hip_runtime.h>
#include <hip/hip_bf16.h>

typedef unsigned short u16;
typedef float f32x4 __attribute__((ext_vector_type(4)));
typedef __bf16 bf16x8 __attribute__((ext_vector_type(8)));
typedef _Float16 f16x8 __attribute__((ext_vector_type(8)));
typedef _Float16 f16x2 __attribute__((ext_vector_type(2)));

union Frag { int4 i; bf16x8 b; f16x8 h; };

__device__ inline u16 f2bf(float f) {
  union { float f; unsigned u; } v; v.f = f;
  unsigned r = v.u + 0x7FFFu + ((v.u >> 16) & 1u);
  return (u16)(r >> 16);
}
__device__ inline unsigned pk_f16(float a, float b) {  // packed f16 {lo=a, hi=b}, RTZ
  return __builtin_bit_cast(unsigned, __builtin_amdgcn_cvt_pkrtz(a, b));
}

// ---------------------------------------------------------------------------
// Projection GEMM body: Y = X @ W.T + bias (X: rows x 128 fp32, W: 128x128)
// mode 0: out f16  head-major  [b][h][row][16]   (q, k)
// mode 1: out f16  transposed  [b][h][16][1024]  (V)
// mode 2: out fp32 row-major   [row][128]        (out-proj)
// ---------------------------------------------------------------------------
__device__ __forceinline__
void proj_body(u16* __restrict__ smem,
               const float* __restrict__ X, const float* __restrict__ W,
               const float* __restrict__ bias, void* __restrict__ out,
               int mode, int innerShift, int rows0)
{
  u16* XL = smem;              // [64][136]
  u16* WL = smem + 64 * 136;   // [128][136]

  const int tid = threadIdx.x;
  const int w = tid >> 6, l = tid & 63, lg = l >> 4, lr = l & 15;

  #pragma unroll
  for (int i = 0; i < 8; ++i) {
    int u = tid + i * 256;
    int rr = u >> 5, c4 = (u & 31) * 4;
    const float4 xv = *(const float4*)(X + (rows0 + rr) * 128 + c4);
    uint2 p;
    p.x = (unsigned)f2bf(xv.x) | ((unsigned)f2bf(xv.y) << 16);
    p.y = (unsigned)f2bf(xv.z) | ((unsigned)f2bf(xv.w) << 16);
    *(uint2*)(XL + rr * 136 + c4) = p;
  }
  #pragma unroll
  for (int i = 0; i < 16; ++i) {
    int u = tid + i * 256;
    int rr = u >> 5, c4 = (u & 31) * 4;
    const float4 xv = *(const float4*)(W + rr * 128 + c4);
    uint2 p;
    p.x = (unsigned)f2bf(xv.x) | ((unsigned)f2bf(xv.y) << 16);
    p.y = (unsigned)f2bf(xv.z) | ((unsigned)f2bf(xv.w) << 16);
    *(uint2*)(WL + rr * 136 + c4) = p;
  }
  __syncthreads();

  Frag a[4];
  #pragma unroll
  for (int kc = 0; kc < 4; ++kc)
    a[kc].i = *(const int4*)(XL + (16 * w + lr) * 136 + kc * 32 + 8 * lg);

  f32x4 acc[8];
  #pragma unroll
  for (int ct = 0; ct < 8; ++ct) {
    f32x4 c = {0.f, 0.f, 0.f, 0.f};
    #pragma unroll
    for (int kc = 0; kc < 4; ++kc) {
      Frag bw;
      bw.i = *(const int4*)(WL + (ct * 16 + lr) * 136 + kc * 32 + 8 * lg);
      c = __builtin_amdgcn_mfma_f32_16x16x32_bf16(a[kc].b, bw.b, c, 0, 0, 0);
    }
    acc[ct] = c;
  }

  if (mode == 2) {
    float* o = (float*)out;
    #pragma unroll
    for (int ct = 0; ct < 8; ++ct) {
      float bn = bias[ct * 16 + lr];
      #pragma unroll
      for (int j = 0; j < 4; ++j) {
        int row = rows0 + 16 * w + 4 * lg + j;
        o[row * 128 + ct * 16 + lr] = acc[ct][j] + bn;
      }
    }
  } else if (mode == 0) {  // f16 head-major (q, k)
    u16* o = (u16*)out;
    const int innerMask = (1 << innerShift) - 1;
    #pragma unroll
    for (int ct = 0; ct < 8; ++ct) {
      float bn = bias[ct * 16 + lr];
      #pragma unroll
      for (int j = 0; j < 4; ++j) {
        int row = rows0 + 16 * w + 4 * lg + j;
        int bI = row >> innerShift, r = row & innerMask;
        o[(((bI * 8 + ct) << innerShift) + r) * 16 + lr] =
            __builtin_bit_cast(u16, (_Float16)(acc[ct][j] + bn));
      }
    }
  } else { // mode 1: f16 transposed via LDS
    __syncthreads();
    u16* YT = smem; // [128][72]
    #pragma unroll
    for (int ct = 0; ct < 8; ++ct) {
      float bn = bias[ct * 16 + lr];
      #pragma unroll
      for (int j = 0; j < 4; ++j)
        YT[(ct * 16 + lr) * 72 + 16 * w + 4 * lg + j] =
            __builtin_bit_cast(u16, (_Float16)(acc[ct][j] + bn));
    }
    __syncthreads();
    u16* o = (u16*)out;
    const int bI = rows0 >> 10, s0 = rows0 & 1023;
    #pragma unroll
    for (int i = 0; i < 4; ++i) {
      int u = tid + i * 256;
      int n = u >> 3, ch = (u & 7) * 8;
      int4 v = *(const int4*)(YT + n * 72 + ch);
      *(int4*)(o + ((bI * 8 + (n >> 4)) * 16 + (n & 15)) * 1024 + s0 + ch) = v;
    }
  }
}

__global__ __launch_bounds__(256, 2)
void proj_qkv(const float* __restrict__ Q, const float* __restrict__ K,
              const float* __restrict__ V,
              const float* __restrict__ Wq, const float* __restrict__ bq,
              const float* __restrict__ Wk, const float* __restrict__ bk,
              const float* __restrict__ Wv, const float* __restrict__ bv,
              u16* __restrict__ qb, u16* __restrict__ kb, u16* __restrict__ vtb)
{
  __shared__ __attribute__((aligned(16))) u16 smem[26112];
  const int bid = blockIdx.x;
  if (bid < 64)       proj_body(smem, Q, Wq, bq, qb,  0,  9, bid * 64);
  else if (bid < 192) proj_body(smem, K, Wk, bk, kb,  0, 10, (bid - 64) * 64);
  else                proj_body(smem, V, Wv, bv, vtb, 1, 10, (bid - 192) * 64);
}

__global__ __launch_bounds__(256, 2)
void proj_out(const float* __restrict__ X, const float* __restrict__ W,
              const float* __restrict__ bias, float* __restrict__ out)
{
  __shared__ __attribute__((aligned(16))) u16 smem[26112];
  proj_body(smem, X, W, bias, out, 2, 9, blockIdx.x * 64);
}

// ---------------------------------------------------------------------------
// Fused attention. Block = (b, h, 16 p-rows); 4 waves.
// Phase A: QK^T (f16 MFMA) -> scores f16 in LDS (gated-on channels only).
// Phase B: stream prev (gate-aware prefetch depth 4); rs fp32 -> rs_out;
//          e = exp(rs): fp32 den (online), packed-f16 e in REGISTERS + LDS.
//          Then attn = e * invd written straight from registers (no 2nd pass),
//          all before the barrier. Barrier only protects PV's LDS reads.
// PV: f16 MFMA over LDS e and f16 V^T; 1/den folded in epilogue.
// ---------------------------------------------------------------------------
__global__ __launch_bounds__(256, 4)
void attn_kernel(const u16* __restrict__ qb, const u16* __restrict__ kb,
                 const u16* __restrict__ vtb, const float* __restrict__ prev,
                 const float* __restrict__ ch_gate,
                 float* __restrict__ rs_out, float* __restrict__ attn_out,
                 float* __restrict__ preout)
{
  __shared__ __attribute__((aligned(16))) u16 SRS[16][1032];
  __shared__ float DenInv[16];
  __shared__ float OutBuf[4][16][20];

  const int bid = blockIdx.x;
  const int vb = (bid & 7) * 256 + (bid >> 3);  // XCD swizzle: one batch per XCD
  const int pt = vb & 31, h = (vb >> 5) & 7, b = vb >> 8;
  const int p0 = pt * 16, ptch = pt >> 2;       // predictor channel
  const int tid = threadIdx.x, w = tid >> 6, l = tid & 63;
  const int lg = l >> 4, lr = l & 15;

  // gate bits (sigmoid(x)>=0.5 <=> x>=0), wave-uniform
  unsigned gbits = 0u;
  #pragma unroll
  for (int j = 0; j < 8; ++j)
    if (ch_gate[ptch * 8 + j] >= 0.f) gbits |= (1u << j);
  gbits = __builtin_amdgcn_readfirstlane(gbits);

  const int r = 4 * w + lg;                      // row this thread streams in B
  const int base = ((b * 512 + p0) * 8 + h) * 1024;
  const float* prow = prev + base + r * 8192;

  // gate-aware prefetch of first 4 prev chunks (channels 0,1)
  const f32x4 zf = {0.f, 0.f, 0.f, 0.f};
  f32x4 pf0 = (gbits & 1u) ? __builtin_nontemporal_load((const f32x4*)(prow +   0 + lr * 4)) : zf;
  f32x4 pf1 = (gbits & 1u) ? __builtin_nontemporal_load((const f32x4*)(prow +  64 + lr * 4)) : zf;
  f32x4 pf2 = (gbits & 2u) ? __builtin_nontemporal_load((const f32x4*)(prow + 128 + lr * 4)) : zf;
  f32x4 pf3 = (gbits & 2u) ? __builtin_nontemporal_load((const f32x4*)(prow + 192 + lr * 4)) : zf;

  // ---- Phase A: QK^T scores (f16) -> LDS, gated-on channels only ----
  Frag aq;
  if (lg < 2) aq.i = *(const int4*)(qb + (((b * 8 + h) * 512 + p0 + lr) * 16 + 8 * lg));
  else        aq.i = make_int4(0, 0, 0, 0);

  const u16* kbase = kb + (b * 8 + h) * 1024 * 16;
  const int sbase = w * 256;

  #pragma unroll 2
  for (int st = 0; st < 16; ++st) {
    const int s0 = sbase + st * 16;
    if (!((gbits >> (s0 >> 7)) & 1u)) continue;
    Frag bk;
    if (lg < 2) bk.i = *(const int4*)(kbase + (s0 + lr) * 16 + 8 * lg);
    else        bk.i = make_int4(0, 0, 0, 0);
    f32x4 zero = {0.f, 0.f, 0.f, 0.f};
    f32x4 d = __builtin_amdgcn_mfma_f32_16x16x32_f16(aq.h, bk.h, zero, 0, 0, 0);
    #pragma unroll
    for (int j = 0; j < 4; ++j)
      SRS[4 * lg + j][s0 + lr] = __builtin_bit_cast(u16, (_Float16)(d[j] * 0.25f));
  }
  __syncthreads();

  // ---- Phase B: stream prev; rs -> global; e (f16) -> regs + LDS; fp32 den ----
  float* rsrow = rs_out + base + r * 8192;
  float den = 0.f;
  uint2 eh[16];

  #pragma unroll
  for (int it = 0; it < 16; ++it) {
    const int s = it * 64 + lr * 4;
    const int ch = it >> 1;
    const bool msk = (ch == ptch);
    if ((gbits >> ch) & 1u) {
      f32x4 pv;
      if      (it == 0) pv = pf0;
      else if (it == 1) pv = pf1;
      else if (it == 2) pv = pf2;
      else if (it == 3) pv = pf3;
      else pv = __builtin_nontemporal_load((const f32x4*)(prow + s));
      union { uint2 u; f16x2 hh[2]; } sc;
      sc.u = *(const uint2*)&SRS[r][s];
      f32x4 rs;
      rs[0] = (float)sc.hh[0][0] + pv[0];
      rs[1] = (float)sc.hh[0][1] + pv[1];
      rs[2] = (float)sc.hh[1][0] + pv[2];
      rs[3] = (float)sc.hh[1][1] + pv[3];
      __builtin_nontemporal_store(rs, (f32x4*)(rsrow + s));
      if (msk) {
        eh[it] = make_uint2(0u, 0u);
      } else {
        float e0 = __expf(rs[0]);
        float e1 = __expf(rs[1]);
        float e2 = __expf(rs[2]);
        float e3 = __expf(rs[3]);
        den += (e0 + e1) + (e2 + e3);
        eh[it].x = pk_f16(e0, e1);
        eh[it].y = pk_f16(e2, e3);
      }
    } else {
      __builtin_nontemporal_store(zf, (f32x4*)(rsrow + s));
      if (msk) eh[it] = make_uint2(0u, 0u);
      else   { eh[it] = make_uint2(0x3C003C00u, 0x3C003C00u); den += 4.f; }
    }
    *(uint2*)&SRS[r][s] = eh[it];
  }

  #pragma unroll
  for (int off = 1; off < 16; off <<= 1)
    den += __shfl_xor(den, off);
  const float invd = 1.f / den;                  // den >= 1 always
  if (lr == 0) DenInv[r] = invd;

  // ---- attn = e * invd, straight from registers (before barrier) ----
  {
    float* arow = attn_out + base + r * 8192;
    #pragma unroll
    for (int it = 0; it < 16; ++it) {
      const int s = it * 64 + lr * 4;
      union { uint2 u; f16x2 hh[2]; } e;
      e.u = eh[it];
      f32x4 o;
      o[0] = (float)e.hh[0][0] * invd;
      o[1] = (float)e.hh[0][1] * invd;
      o[2] = (float)e.hh[1][0] * invd;
      o[3] = (float)e.hh[1][1] * invd;
      __builtin_nontemporal_store(o, (f32x4*)(arow + s));
    }
  }
  __syncthreads();                               // e visible to all waves (PV)

  // ---- PV: acc = sum_s e[p][s] * v[s][d] (f16), 1/den folded at output ----
  f32x4 acc = {0.f, 0.f, 0.f, 0.f};
  const u16* vbase = vtb + ((b * 8 + h) * 16 + lr) * 1024;
  #pragma unroll
  for (int kc = 0; kc < 8; ++kc) {
    Frag pa, bv;
    pa.i = *(const int4*)(&SRS[lr][sbase + kc * 32 + 8 * lg]);
    bv.i = *(const int4*)(vbase + sbase + kc * 32 + 8 * lg);
    acc = __builtin_amdgcn_mfma_f32_16x16x32_f16(pa.h, bv.h, acc, 0, 0, 0);
  }
  #pragma unroll
  for (int j = 0; j < 4; ++j) OutBuf[w][4 * lg + j][lr] = acc[j];
  __syncthreads();
  {
    const int pr = tid >> 4, dd = tid & 15;
    float o = (OutBuf[0][pr][dd] + OutBuf[1][pr][dd] +
               OutBuf[2][pr][dd] + OutBuf[3][pr][dd]) * DenInv[pr];
    preout[((b * 512 + p0 + pr) * 8 + h) * 16 + dd] = o;
  }
}

// ---------------------------------------------------------------------------
extern "C" void kernel_launch(void* const* d_in, const int* in_sizes, int n_in,
                              void* d_out, int out_size, void* d_ws, size_t ws_size,
                              hipStream_t stream)
{
  (void)in_sizes; (void)n_in; (void)out_size; (void)ws_size;
  const float* Q       = (const float*)d_in[0];
  const float* K       = (const float*)d_in[1];
  const float* V       = (const float*)d_in[2];
  const float* prev    = (const float*)d_in[3];
  const float* Wq      = (const float*)d_in[5];
  const float* bq      = (const float*)d_in[6];
  const float* Wk      = (const float*)d_in[7];
  const float* bk      = (const float*)d_in[8];
  const float* Wv      = (const float*)d_in[9];
  const float* bv      = (const float*)d_in[10];
  const float* Wo      = (const float*)d_in[11];
  const float* bo      = (const float*)d_in[12];
  const float* ch_gate = (const float*)d_in[13];

  u16*   qb     = (u16*)d_ws;                        // 1 MB f16
  u16*   kb     = qb + 524288;                       // 2 MB f16
  u16*   vtb    = kb + 1048576;                      // 2 MB f16
  float* preout = (float*)((char*)d_ws + 5242880);   // 2 MB fp32

  float* outp     = (float*)d_out;          // (B,P,128)
  float* attn_out = outp + 524288;          // (B,P,H,S)
  float* rs_out   = outp + 34078720;        // (B,P,H,S)

  proj_qkv<<<320, 256, 0, stream>>>(Q, K, V, Wq, bq, Wk, bk, Wv, bv,
                                    qb, kb, vtb);
  attn_kernel<<<2048, 256, 0, stream>>>(qb, kb, vtb, prev, ch_gate,
                                        rs_out, attn_out, preout);
  proj_out<<<64, 256, 0, stream>>>(preout, Wo, bo, outp);
}